// Round 1
// baseline (230.022 us; speedup 1.0000x reference)
//
#include <hip/hip_runtime.h>
#include <hip/hip_bf16.h>

#define DD 128
#define HH 4
#define DHH 32
#define NS 320
#define NT (NS*NS)
#define EPSF 1e-5f

typedef __bf16 bf16;
typedef __bf16 bf16x8 __attribute__((ext_vector_type(8)));
typedef float f32x4 __attribute__((ext_vector_type(4)));

#define MFMA __builtin_amdgcn_mfma_f32_16x16x32_bf16

// ---------------------------------------------------------------- weight pack
// Wt[m][c][k] = W_m[k][c] in bf16 (m: 0=Wq 1=Wk 2=Wv 3=Wg), Wot[c][k] = Wo[k][c]
__global__ __launch_bounds__(256) void k_pack(
    const float* __restrict__ Wq, const float* __restrict__ Wk,
    const float* __restrict__ Wv, const float* __restrict__ Wg,
    const float* __restrict__ Wo, bf16* __restrict__ Wt, bf16* __restrict__ Wot)
{
    int idx = blockIdx.x*256 + threadIdx.x;
    if (idx >= 5*16384) return;
    int m = idx >> 14;
    int r = idx & 16383;
    int c = r >> 7, k = r & 127;
    const float* s = (m==0)?Wq:(m==1)?Wk:(m==2)?Wv:(m==3)?Wg:Wo;
    float v = s[k*DD + c];
    if (m < 4) Wt[idx] = (bf16)v; else Wot[r] = (bf16)v;
}

// ---------------------------------------------------------------- LN1 + bias B
// one wave per token: z = LN(pair)*g1+b1 (bf16 out), B[l,h,j] = z . Wb[:,h] (f32)
__global__ __launch_bounds__(256) void k_ln1(
    const float* __restrict__ pair, const float* __restrict__ g1,
    const float* __restrict__ b1, const float* __restrict__ Wb,
    bf16* __restrict__ z, float* __restrict__ Bt)
{
    int lane = threadIdx.x & 63;
    int tok = blockIdx.x*4 + (threadIdx.x >> 6);
    const float* row = pair + (size_t)tok*DD;
    float2 x = *(const float2*)(row + lane*2);
    float s1 = x.x + x.y, s2 = x.x*x.x + x.y*x.y;
    #pragma unroll
    for (int m=1; m<64; m<<=1) { s1 += __shfl_xor(s1, m); s2 += __shfl_xor(s2, m); }
    float mean = s1*(1.f/DD);
    float rstd = rsqrtf(s2*(1.f/DD) - mean*mean + EPSF);
    float z0 = (x.x-mean)*rstd*g1[lane*2]   + b1[lane*2];
    float z1 = (x.y-mean)*rstd*g1[lane*2+1] + b1[lane*2+1];
    union { bf16 h[2]; unsigned int u; } pk;
    pk.h[0] = (bf16)z0; pk.h[1] = (bf16)z1;
    *(unsigned int*)(z + (size_t)tok*DD + lane*2) = pk.u;
    // bias: B[h] = sum_d z_f32[d]*Wb[d][h]
    float4 wa = *(const float4*)(Wb + lane*8);
    float4 wb = *(const float4*)(Wb + lane*8 + 4);
    float c0 = z0*wa.x + z1*wb.x;
    float c1 = z0*wa.y + z1*wb.y;
    float c2 = z0*wa.z + z1*wb.z;
    float c3 = z0*wa.w + z1*wb.w;
    #pragma unroll
    for (int m=1; m<64; m<<=1) {
        c0 += __shfl_xor(c0,m); c1 += __shfl_xor(c1,m);
        c2 += __shfl_xor(c2,m); c3 += __shfl_xor(c3,m);
    }
    if (lane < 4) {
        float bv = (lane==0)?c0:(lane==1)?c1:(lane==2)?c2:c3;
        int l = tok/NS, j = tok - l*NS;
        Bt[(l*HH + lane)*NS + j] = bv;
    }
}

// ---------------------------------------------------------------- projections
// C[64 tokens][128 cols] = z @ W_m ; m = blockIdx.y selects Q/K/V/G(sigmoid)
__global__ __launch_bounds__(256) void k_proj(
    const bf16* __restrict__ z, const bf16* __restrict__ Wt, const float* __restrict__ bg,
    bf16* __restrict__ Q, bf16* __restrict__ K, bf16* __restrict__ V, bf16* __restrict__ G)
{
    __shared__ __attribute__((aligned(16))) bf16 As[64*136];   // +8 pad: bank spread
    __shared__ __attribute__((aligned(16))) bf16 Bs[128*136];
    int t = threadIdx.x, lane = t & 63, w = t >> 6;
    int l15 = lane & 15, lhi = lane >> 4;
    int tok0 = blockIdx.x * 64;
    int m = blockIdx.y;
    const bf16* Wm = Wt + m*16384;
    #pragma unroll
    for (int it=0; it<4; ++it) {
        int q = t + it*256;
        int r = q >> 4, c8 = (q & 15)*8;
        *(uint4*)(As + r*136 + c8) = *(const uint4*)(z + (size_t)(tok0+r)*DD + c8);
    }
    #pragma unroll
    for (int it=0; it<8; ++it) {
        int q = t + it*256;
        int r = q >> 4, c8 = (q & 15)*8;
        *(uint4*)(Bs + r*136 + c8) = *(const uint4*)(Wm + r*DD + c8);
    }
    __syncthreads();
    f32x4 zero = {0.f,0.f,0.f,0.f};
    f32x4 acc[4][2];
    #pragma unroll
    for (int i=0;i<4;++i) { acc[i][0] = zero; acc[i][1] = zero; }
    #pragma unroll
    for (int ks=0; ks<4; ++ks) {
        int ko = ks*32 + lhi*8;
        bf16x8 bf0 = *(const bf16x8*)(Bs + (w*32 + l15)*136 + ko);
        bf16x8 bf1 = *(const bf16x8*)(Bs + (w*32 + 16 + l15)*136 + ko);
        #pragma unroll
        for (int it=0; it<4; ++it) {
            bf16x8 af = *(const bf16x8*)(As + (it*16 + l15)*136 + ko);
            acc[it][0] = MFMA(af, bf0, acc[it][0], 0,0,0);
            acc[it][1] = MFMA(af, bf1, acc[it][1], 0,0,0);
        }
    }
    bf16* out = (m==0)?Q:(m==1)?K:(m==2)?V:G;
    #pragma unroll
    for (int it=0; it<4; ++it)
      #pragma unroll
      for (int jt=0; jt<2; ++jt) {
        int col = w*32 + jt*16 + l15;
        #pragma unroll
        for (int r=0; r<4; ++r) {
            float vv = acc[it][jt][r];
            if (m == 3) vv = 1.f/(1.f + __expf(-(vv + bg[col])));
            out[(size_t)(tok0 + it*16 + lhi*4 + r)*DD + col] = (bf16)vv;
        }
      }
}

// ---------------------------------------------------------------- attention
// block = (l, h, 64-row i-tile); wave w owns i-rows [w*16, w*16+16)
__global__ __launch_bounds__(256) void k_attn(
    const bf16* __restrict__ Q, const bf16* __restrict__ K,
    const bf16* __restrict__ V, const float* __restrict__ Bt, bf16* __restrict__ AO)
{
    __shared__ __attribute__((aligned(16))) char smem[22272 + 41984];
    bf16* Vt  = (bf16*)smem;             // [32 d][328] V transposed
    float* Bsh = (float*)(smem + 20992); // [320] bias row
    bf16* KP  = (bf16*)(smem + 22272);   // union: K [320][40]  ->  P [64][328]
    int t = threadIdx.x, lane = t & 63, w = t >> 6;
    int l15 = lane & 15, lhi = lane >> 4;
    int l = blockIdx.x, h = blockIdx.y;
    int i0 = blockIdx.z * 64;
    const size_t rowbase = (size_t)l * NS;
    #pragma unroll
    for (int it=0; it<5; ++it) {             // K: [320][40]
        int q = t + it*256;
        int j = q >> 2, d8 = (q & 3)*8;
        *(uint4*)(KP + j*40 + d8) = *(const uint4*)(K + (rowbase + j)*DD + h*DHH + d8);
    }
    #pragma unroll
    for (int it=0; it<5; ++it) {             // V transposed
        int q = t + it*256;
        int j = q >> 2, d8 = (q & 3)*8;
        bf16x8 vv = *(const bf16x8*)(V + (rowbase + j)*DD + h*DHH + d8);
        #pragma unroll
        for (int e=0; e<8; ++e) Vt[(d8+e)*328 + j] = vv[e];
    }
    for (int j=t; j<NS; j+=256) Bsh[j] = Bt[(l*HH + h)*NS + j];
    __syncthreads();
    // Q fragment straight from global (one per wave, reused 20x)
    bf16x8 qf = *(const bf16x8*)(Q + (rowbase + i0 + w*16 + l15)*DD + h*DHH + lhi*8);
    f32x4 zero = {0.f,0.f,0.f,0.f};
    f32x4 s[20];
    #pragma unroll
    for (int jt=0; jt<20; ++jt) {
        bf16x8 kf = *(const bf16x8*)(KP + (jt*16 + l15)*40 + lhi*8);
        s[jt] = MFMA(qf, kf, zero, 0,0,0);
    }
    __syncthreads();                         // all waves done reading K -> P may overwrite
    const float scale = 0.17677669529663687f; // 1/sqrt(32)
    #pragma unroll
    for (int jt=0; jt<20; ++jt) {
        float bb = Bsh[jt*16 + l15];
        #pragma unroll
        for (int r=0;r<4;++r) s[jt][r] = s[jt][r]*scale + bb;
    }
    bf16* Ps = KP;
    #pragma unroll
    for (int r=0; r<4; ++r) {
        float mx = -1e30f;
        #pragma unroll
        for (int jt=0;jt<20;++jt) mx = fmaxf(mx, s[jt][r]);
        #pragma unroll
        for (int msk=1; msk<16; msk<<=1) mx = fmaxf(mx, __shfl_xor(mx, msk));
        float sum = 0.f;
        #pragma unroll
        for (int jt=0;jt<20;++jt) { float p = __expf(s[jt][r]-mx); s[jt][r] = p; sum += p; }
        #pragma unroll
        for (int msk=1; msk<16; msk<<=1) sum += __shfl_xor(sum, msk);
        float inv = 1.f / sum;
        int irow = w*16 + lhi*4 + r;
        #pragma unroll
        for (int jt=0;jt<20;++jt) Ps[irow*328 + jt*16 + l15] = (bf16)(s[jt][r]*inv);
    }
    __syncthreads();
    f32x4 o0 = zero, o1 = zero;
    #pragma unroll
    for (int ks=0; ks<10; ++ks) {
        bf16x8 pf = *(const bf16x8*)(Ps + (w*16 + l15)*328 + ks*32 + lhi*8);
        bf16x8 v0 = *(const bf16x8*)(Vt + l15*328 + ks*32 + lhi*8);
        bf16x8 v1 = *(const bf16x8*)(Vt + (16 + l15)*328 + ks*32 + lhi*8);
        o0 = MFMA(pf, v0, o0, 0,0,0);
        o1 = MFMA(pf, v1, o1, 0,0,0);
    }
    #pragma unroll
    for (int r=0;r<4;++r) {
        size_t orow = (rowbase + i0 + w*16 + lhi*4 + r)*DD + h*DHH;
        AO[orow + l15]      = (bf16)o0[r];
        AO[orow + 16 + l15] = (bf16)o1[r];
    }
}

// ---------------------------------------------------------------- out GEMM + LN2
__global__ __launch_bounds__(256) void k_out(
    const bf16* __restrict__ AO, const bf16* __restrict__ G,
    const bf16* __restrict__ Wot, const float* __restrict__ bo,
    const float* __restrict__ pair, const float* __restrict__ g2,
    const float* __restrict__ b2, float* __restrict__ out)
{
    __shared__ __attribute__((aligned(16))) char smem[52224];
    bf16* As = (bf16*)smem;             // [64][136]
    bf16* Bs = (bf16*)(smem + 17408);   // [128][136]
    float* Cs = (float*)smem;           // [64][136] f32 overlay (post-MFMA)
    int t = threadIdx.x, lane = t & 63, w = t >> 6;
    int l15 = lane & 15, lhi = lane >> 4;
    int tok0 = blockIdx.x*64;
    #pragma unroll
    for (int it=0; it<4; ++it) {        // A = gate * attn_out (bf16)
        int q = t + it*256;
        int r = q >> 4, c8 = (q & 15)*8;
        bf16x8 a = *(const bf16x8*)(AO + (size_t)(tok0+r)*DD + c8);
        bf16x8 g = *(const bf16x8*)(G  + (size_t)(tok0+r)*DD + c8);
        bf16x8 p;
        #pragma unroll
        for (int e=0;e<8;++e) p[e] = (bf16)((float)a[e]*(float)g[e]);
        *(bf16x8*)(As + r*136 + c8) = p;
    }
    #pragma unroll
    for (int it=0; it<8; ++it) {
        int q = t + it*256;
        int r = q >> 4, c8 = (q & 15)*8;
        *(uint4*)(Bs + r*136 + c8) = *(const uint4*)(Wot + r*DD + c8);
    }
    __syncthreads();
    f32x4 zero = {0.f,0.f,0.f,0.f};
    f32x4 acc[4][2];
    #pragma unroll
    for (int i=0;i<4;++i) { acc[i][0] = zero; acc[i][1] = zero; }
    #pragma unroll
    for (int ks=0; ks<4; ++ks) {
        int ko = ks*32 + lhi*8;
        bf16x8 bf0 = *(const bf16x8*)(Bs + (w*32 + l15)*136 + ko);
        bf16x8 bf1 = *(const bf16x8*)(Bs + (w*32 + 16 + l15)*136 + ko);
        #pragma unroll
        for (int it=0; it<4; ++it) {
            bf16x8 af = *(const bf16x8*)(As + (it*16 + l15)*136 + ko);
            acc[it][0] = MFMA(af, bf0, acc[it][0], 0,0,0);
            acc[it][1] = MFMA(af, bf1, acc[it][1], 0,0,0);
        }
    }
    __syncthreads();                     // done reading As/Bs -> Cs overlay safe
    #pragma unroll
    for (int it=0;it<4;++it)
      #pragma unroll
      for (int jt=0;jt<2;++jt) {
        int col = w*32 + jt*16 + l15;
        float bov = bo[col];
        #pragma unroll
        for (int r=0;r<4;++r)
            Cs[(it*16 + lhi*4 + r)*136 + col] = acc[it][jt][r] + bov;
      }
    __syncthreads();
    // LN2: 4 lanes per row, lane sub covers cols {sub*4 + 16k}
    int row = t >> 2, sub = t & 3;
    size_t grow = (size_t)(tok0 + row)*DD;
    float4 xs[8];
    float s1 = 0.f, s2 = 0.f;
    #pragma unroll
    for (int k=0;k<8;++k) {
        int c = sub*4 + k*16;
        float4 p = *(const float4*)(pair + grow + c);
        float4 cv = *(const float4*)(Cs + row*136 + c);
        float4 x;
        x.x = p.x + cv.x; x.y = p.y + cv.y; x.z = p.z + cv.z; x.w = p.w + cv.w;
        xs[k] = x;
        s1 += x.x + x.y + x.z + x.w;
        s2 += x.x*x.x + x.y*x.y + x.z*x.z + x.w*x.w;
    }
    s1 += __shfl_xor(s1, 1); s2 += __shfl_xor(s2, 1);
    s1 += __shfl_xor(s1, 2); s2 += __shfl_xor(s2, 2);
    float mean = s1*(1.f/DD);
    float rstd = rsqrtf(s2*(1.f/DD) - mean*mean + EPSF);
    #pragma unroll
    for (int k=0;k<8;++k) {
        int c = sub*4 + k*16;
        float4 gg = *(const float4*)(g2 + c);
        float4 bb = *(const float4*)(b2 + c);
        float4 y;
        y.x = (xs[k].x-mean)*rstd*gg.x + bb.x;
        y.y = (xs[k].y-mean)*rstd*gg.y + bb.y;
        y.z = (xs[k].z-mean)*rstd*gg.z + bb.z;
        y.w = (xs[k].w-mean)*rstd*gg.w + bb.w;
        *(float4*)(out + grow + c) = y;
    }
}

extern "C" void kernel_launch(void* const* d_in, const int* in_sizes, int n_in,
                              void* d_out, int out_size, void* d_ws, size_t ws_size,
                              hipStream_t stream)
{
    const float* pair = (const float*)d_in[0];
    const float* g1   = (const float*)d_in[1];
    const float* b1   = (const float*)d_in[2];
    const float* Wq   = (const float*)d_in[3];
    const float* Wk   = (const float*)d_in[4];
    const float* Wv   = (const float*)d_in[5];
    const float* Wb   = (const float*)d_in[6];
    const float* Wg   = (const float*)d_in[7];
    const float* bg   = (const float*)d_in[8];
    const float* Wo   = (const float*)d_in[9];
    const float* bo   = (const float*)d_in[10];
    const float* g2   = (const float*)d_in[11];
    const float* b2   = (const float*)d_in[12];
    float* out = (float*)d_out;

    char* ws = (char*)d_ws;
    size_t off = 0;
    auto alloc = [&](size_t n) { char* p = ws + off; off = (off + n + 255) & ~(size_t)255; return p; };
    bf16* z   = (bf16*)alloc((size_t)NT*DD*2);
    bf16* Qb  = (bf16*)alloc((size_t)NT*DD*2);
    bf16* Kb  = (bf16*)alloc((size_t)NT*DD*2);
    bf16* Vb  = (bf16*)alloc((size_t)NT*DD*2);
    bf16* Gb  = (bf16*)alloc((size_t)NT*DD*2);
    bf16* AOb = (bf16*)alloc((size_t)NT*DD*2);
    float* Bt = (float*)alloc((size_t)NS*HH*NS*4);
    bf16* Wt  = (bf16*)alloc(4*16384*2);
    bf16* Wot = (bf16*)alloc(16384*2);

    k_pack<<<320, 256, 0, stream>>>(Wq, Wk, Wv, Wg, Wo, Wt, Wot);
    k_ln1<<<NT/4, 256, 0, stream>>>(pair, g1, b1, Wb, z, Bt);
    k_proj<<<dim3(NT/64, 4), 256, 0, stream>>>(z, Wt, bg, Qb, Kb, Vb, Gb);
    k_attn<<<dim3(NS, HH, NS/64), 256, 0, stream>>>(Qb, Kb, Vb, Bt, AOb);
    k_out<<<NT/64, 256, 0, stream>>>(AOb, Gb, Wot, bo, pair, g2, b2, out);
}